// Round 2
// baseline (565.889 us; speedup 1.0000x reference)
//
#include <hip/hip_runtime.h>

typedef unsigned short u16;
typedef unsigned int   u32;
typedef __attribute__((ext_vector_type(4))) float  f32x4;
typedef __attribute__((ext_vector_type(8))) __bf16 bf16x8;

// ---------------- constants ----------------
#define BATCH 8
#define SEQ   2048
#define DMODEL 1024
#define DK    512
#define DV    512
// softmax scale = 1/sqrt(512)
#define SCALE 0.044194173824159216f

__device__ __forceinline__ u16 f2bf(float f) {
  u32 u = __float_as_uint(f);
  return (u16)((u + 0x7fffu + ((u >> 16) & 1u)) >> 16);
}

// mask dtype mode: 0 = int32, 1 = uint8, 2 = float32
__device__ __forceinline__ bool read_mask(const void* p, int idx, int mode) {
  if (mode == 1) return ((const unsigned char*)p)[idx] != 0;
  if (mode == 2) return ((const float*)p)[idx] != 0.0f;
  return ((const int*)p)[idx] != 0;
}

// ---------------- kernel 0: detect mask dtype ----------------
__global__ void detect_mode(const int* __restrict__ qp, int* __restrict__ flag) {
  __shared__ int f;
  if (threadIdx.x == 0) f = 0;
  __syncthreads();
  int local = 0;
  for (int i = threadIdx.x; i < 4096; i += 256) {
    int v = qp[i];
    if (v == 0x3F800000) local |= 2;                      // 1.0f pattern -> float32
    else if (v != 0 && v != 1 && v != -1) local |= 1;     // packed bytes -> uint8
  }
  if (local) atomicOr(&f, local);
  __syncthreads();
  if (threadIdx.x == 0) {
    int m = 0;
    if (f & 2) m = 2; else if (f & 1) m = 1;
    *flag = m;
  }
}

// ---------------- kernel 1: W [1024][512] f32 -> Wt [512][1024] bf16 ----------------
__global__ __launch_bounds__(256) void wt_transpose(const float* __restrict__ W0,
                                                    const float* __restrict__ W1,
                                                    const float* __restrict__ W2,
                                                    u16* __restrict__ dst) {
  const float* W = (blockIdx.z == 0) ? W0 : (blockIdx.z == 1) ? W1 : W2;
  u16* out = dst + (size_t)blockIdx.z * (DK * DMODEL);
  __shared__ float T[32][33];
  int k0 = blockIdx.x * 32, n0 = blockIdx.y * 32;
  int tx = threadIdx.x, ty = threadIdx.y; // (32,8)
#pragma unroll
  for (int i = 0; i < 4; ++i) {
    int r = ty + i * 8;
    T[r][tx] = W[(size_t)(k0 + r) * DK + n0 + tx];
  }
  __syncthreads();
#pragma unroll
  for (int i = 0; i < 4; ++i) {
    int r = ty + i * 8;
    out[(size_t)(n0 + r) * DMODEL + k0 + tx] = f2bf(T[tx][r]);
  }
}

// ---------------- kernel 2: projections, NT MFMA GEMM ----------------
__global__ __launch_bounds__(256) void proj_gemm(const float* __restrict__ sq,
                                                 const float* __restrict__ skv,
                                                 const u16* __restrict__ Wts,
                                                 u16* __restrict__ outs) {
  int z = blockIdx.z;
  const float* A = (z == 0) ? sq : skv;
  const u16* Wt = Wts + (size_t)z * (DK * DMODEL);
  u16* out = outs + (size_t)z * ((size_t)BATCH * SEQ * DK);
  int n0 = blockIdx.x * 128, m0 = blockIdx.y * 128;
  __shared__ __align__(16) u16 As[128 * 40];
  __shared__ __align__(16) u16 Bs[128 * 40];
  int tid = threadIdx.x, lane = tid & 63, w = tid >> 6;
  int wm = w & 1, wn = w >> 1;
  int l15 = lane & 15, lg = lane >> 4;
  f32x4 acc[4][4];
#pragma unroll
  for (int m = 0; m < 4; ++m)
#pragma unroll
    for (int n = 0; n < 4; ++n) acc[m][n] = (f32x4)0.0f;

  for (int k0 = 0; k0 < DMODEL; k0 += 32) {
    __syncthreads();
#pragma unroll
    for (int t = 0; t < 4; ++t) {
      int idx = t * 256 + tid; int r = idx >> 3, c4 = idx & 7;
      f32x4 v = *(const f32x4*)(A + (size_t)(m0 + r) * DMODEL + k0 + c4 * 4);
      u32* d = (u32*)(As + r * 40 + c4 * 4);
      d[0] = (u32)f2bf(v[0]) | ((u32)f2bf(v[1]) << 16);
      d[1] = (u32)f2bf(v[2]) | ((u32)f2bf(v[3]) << 16);
    }
#pragma unroll
    for (int t = 0; t < 2; ++t) {
      int idx = t * 256 + tid; int r = idx >> 2, c = idx & 3;
      uint4 v = *(const uint4*)(Wt + (size_t)(n0 + r) * DMODEL + k0 + c * 8);
      *(uint4*)(Bs + r * 40 + c * 8) = v;
    }
    __syncthreads();
    bf16x8 af[4], bfv[4];
#pragma unroll
    for (int m = 0; m < 4; ++m)
      af[m] = *(const bf16x8*)(As + (wm * 64 + m * 16 + l15) * 40 + lg * 8);
#pragma unroll
    for (int n = 0; n < 4; ++n)
      bfv[n] = *(const bf16x8*)(Bs + (wn * 64 + n * 16 + l15) * 40 + lg * 8);
#pragma unroll
    for (int m = 0; m < 4; ++m)
#pragma unroll
      for (int n = 0; n < 4; ++n)
        acc[m][n] = __builtin_amdgcn_mfma_f32_16x16x32_bf16(af[m], bfv[n], acc[m][n], 0, 0, 0);
  }
#pragma unroll
  for (int m = 0; m < 4; ++m)
#pragma unroll
    for (int n = 0; n < 4; ++n) {
      int col = n0 + wn * 64 + n * 16 + l15;
#pragma unroll
      for (int r = 0; r < 4; ++r) {
        int row = m0 + wm * 64 + m * 16 + lg * 4 + r;
        out[(size_t)row * DK + col] = f2bf(acc[m][n][r]);
      }
    }
}

// ---------------- kernel 3: V [16384][512] -> Vt [8][512][2048] (bf16) ----------------
__global__ __launch_bounds__(256) void v_transpose(const u16* __restrict__ Vb,
                                                   u16* __restrict__ Vt) {
  __shared__ __align__(16) u16 T[64 * 66];
  int d0 = blockIdx.x * 64;
  int srow = blockIdx.y * 64;
  int b = srow >> 11;
  int sl = srow & 2047;
  int tid = threadIdx.x;
#pragma unroll
  for (int t = 0; t < 2; ++t) {
    int idx = t * 256 + tid; int r = idx >> 3, c8 = idx & 7;
    uint4 v = *(const uint4*)(Vb + (size_t)(srow + r) * DV + d0 + c8 * 8);
    u32* d = (u32*)(T + r * 66 + c8 * 8);
    d[0] = v.x; d[1] = v.y; d[2] = v.z; d[3] = v.w;
  }
  __syncthreads();
#pragma unroll
  for (int t = 0; t < 2; ++t) {
    int idx = t * 256 + tid; int dr = idx >> 3, c8 = idx & 7;
    u16 tmp[8] __attribute__((aligned(16)));
#pragma unroll
    for (int jj = 0; jj < 8; ++jj) tmp[jj] = T[(c8 * 8 + jj) * 66 + dr];
    *(uint4*)(Vt + (size_t)b * (DV * SEQ) + (size_t)(d0 + dr) * SEQ + sl + c8 * 8) =
        *(const uint4*)tmp;
  }
}

// ---------------- kernel 4: flash attention, LDS-free Q/K/V ----------------
// 32 q-rows/block, Tk=64, 4 waves. Wave w: keys w*16..w*16+15 (S phase),
// dv slices w*64..+63 of each 256-chunk (PV phase). Q frags resident in VGPRs.
// QKV read directly global->fragment (L2-resident, 16B/lane loads).
// LDS: only P (32x72 bf16) + cross-wave partials (32x4 f32).
__global__ __launch_bounds__(256, 2) void attn_kernel(
    const u16* __restrict__ Qb, const u16* __restrict__ Kb,
    const u16* __restrict__ Vt, const void* __restrict__ qpad,
    const void* __restrict__ kvpad, const int* __restrict__ flag,
    float* __restrict__ out) {
  __shared__ __align__(16) u16 Pbuf[32 * 72];
  __shared__ __align__(16) float part[32 * 4];

  int tid = threadIdx.x;
  int lane = tid & 63, w = tid >> 6;
  int l15 = lane & 15, lg = lane >> 4;
  int bi = blockIdx.x;
  int b = bi & 7, j = bi >> 3;
  int qt = (j < 32) ? j : 95 - j;   // causal-balanced pairing per CU
  int q0 = qt * 32;
  int mode = *flag;

  // ---- load Q fragments once: 32 rows x 512 d -> 128 VGPRs ----
  bf16x8 q[2][16];
#pragma unroll
  for (int m = 0; m < 2; ++m) {
    const u16* qp = Qb + (size_t)(b * SEQ + q0 + m * 16 + l15) * DK + lg * 8;
#pragma unroll
    for (int ks = 0; ks < 16; ++ks) q[m][ks] = *(const bf16x8*)(qp + ks * 32);
  }

  f32x4 o[2][8];
#pragma unroll
  for (int m = 0; m < 2; ++m)
#pragma unroll
    for (int n = 0; n < 8; ++n) o[m][n] = (f32x4)0.0f;

  float mo[2][4], lsum[2][4];
#pragma unroll
  for (int m = 0; m < 2; ++m)
#pragma unroll
    for (int r = 0; r < 4; ++r) { mo[m][r] = -1e38f; lsum[m][r] = 0.0f; }

  const u16* Vbase = Vt + (size_t)b * (DV * SEQ);
  int nkt = (q0 + 95) >> 6;

  for (int kt = 0; kt < nkt; ++kt) {
    int k0 = kt * 64;
    int key = k0 + w * 16 + l15;

    // ---- S = Q K^T : direct-global K fragments ----
    f32x4 s0 = (f32x4)0.0f, s1 = (f32x4)0.0f;
    {
      const u16* kp = Kb + (size_t)(b * SEQ + key) * DK + lg * 8;
#pragma unroll
      for (int ks = 0; ks < 16; ++ks) {
        bf16x8 bk = *(const bf16x8*)(kp + ks * 32);
        s0 = __builtin_amdgcn_mfma_f32_16x16x32_bf16(q[0][ks], bk, s0, 0, 0, 0);
        s1 = __builtin_amdgcn_mfma_f32_16x16x32_bf16(q[1][ks], bk, s1, 0, 0, 0);
      }
    }

    // ---- scale + mask (in-register) ----
    bool kvm = read_mask(kvpad, b * SEQ + key, mode);
    float sv[2][4];
#pragma unroll
    for (int m = 0; m < 2; ++m)
#pragma unroll
      for (int r = 0; r < 4; ++r) {
        int qg = q0 + m * 16 + lg * 4 + r;
        float s = (m == 0 ? s0[r] : s1[r]) * SCALE;
        sv[m][r] = (kvm || key > qg) ? -__builtin_inff() : s;
      }

    // ---- wave-local row max across the 16 key lanes ----
    float wm[2][4];
#pragma unroll
    for (int m = 0; m < 2; ++m)
#pragma unroll
      for (int r = 0; r < 4; ++r) wm[m][r] = sv[m][r];
#pragma unroll
    for (int d = 1; d < 16; d <<= 1)
#pragma unroll
      for (int m = 0; m < 2; ++m)
#pragma unroll
        for (int r = 0; r < 4; ++r) wm[m][r] = fmaxf(wm[m][r], __shfl_xor(wm[m][r], d));

    if (l15 == 0) {
#pragma unroll
      for (int m = 0; m < 2; ++m)
#pragma unroll
        for (int r = 0; r < 4; ++r) part[(m * 16 + lg * 4 + r) * 4 + w] = wm[m][r];
    }
    __syncthreads(); // B1: cross-wave max visible; prior-kt P reads done

    // ---- new running max, alpha, p, wave-local sums ----
    float al[2][4], ws[2][4];
#pragma unroll
    for (int m = 0; m < 2; ++m)
#pragma unroll
      for (int r = 0; r < 4; ++r) {
        int row = m * 16 + lg * 4 + r;
        f32x4 pm = *(const f32x4*)&part[row * 4];
        float tm = fmaxf(fmaxf(pm[0], pm[1]), fmaxf(pm[2], pm[3]));
        float mn = fmaxf(mo[m][r], fmaxf(tm, -1e38f)); // clamp keeps masked rows finite
        al[m][r] = __expf(mo[m][r] - mn);
        mo[m][r] = mn;
        float p = __expf(sv[m][r] - mn);
        ws[m][r] = p;
        Pbuf[row * 72 + w * 16 + l15] = f2bf(p);
      }
#pragma unroll
    for (int d = 1; d < 16; d <<= 1)
#pragma unroll
      for (int m = 0; m < 2; ++m)
#pragma unroll
        for (int r = 0; r < 4; ++r) ws[m][r] += __shfl_xor(ws[m][r], d);
#pragma unroll
    for (int m = 0; m < 2; ++m)
#pragma unroll
      for (int r = 0; r < 4; ++r) lsum[m][r] = lsum[m][r] * al[m][r] + ws[m][r];

    // ---- rescale O ----
#pragma unroll
    for (int m = 0; m < 2; ++m)
#pragma unroll
      for (int n = 0; n < 8; ++n)
#pragma unroll
        for (int r = 0; r < 4; ++r) o[m][n][r] *= al[m][r];

    __syncthreads(); // B2: P visible

    // ---- O += P V : direct-global V^T fragments ----
#pragma unroll
    for (int c = 0; c < 2; ++c) {
#pragma unroll
      for (int ks = 0; ks < 2; ++ks) {
        bf16x8 pa0 = *(const bf16x8*)(Pbuf + (l15) * 72 + ks * 32 + lg * 8);
        bf16x8 pa1 = *(const bf16x8*)(Pbuf + (16 + l15) * 72 + ks * 32 + lg * 8);
#pragma unroll
        for (int n = 0; n < 4; ++n) {
          int dv = c * 256 + w * 64 + n * 16 + l15;
          bf16x8 bv = *(const bf16x8*)(Vbase + (size_t)dv * SEQ + k0 + ks * 32 + lg * 8);
          o[0][c * 4 + n] = __builtin_amdgcn_mfma_f32_16x16x32_bf16(pa0, bv, o[0][c * 4 + n], 0, 0, 0);
          o[1][c * 4 + n] = __builtin_amdgcn_mfma_f32_16x16x32_bf16(pa1, bv, o[1][c * 4 + n], 0, 0, 0);
        }
      }
    }
  }

  // ---- epilogue: cross-wave l sum, normalize, masks ----
  __syncthreads(); // part region reuse
  if (l15 == 0) {
#pragma unroll
    for (int m = 0; m < 2; ++m)
#pragma unroll
      for (int r = 0; r < 4; ++r) part[(m * 16 + lg * 4 + r) * 4 + w] = lsum[m][r];
  }
  __syncthreads();
  {
    float f[2][4];
#pragma unroll
    for (int m = 0; m < 2; ++m)
#pragma unroll
      for (int r = 0; r < 4; ++r) {
        int row = m * 16 + lg * 4 + r;
        f32x4 pl = *(const f32x4*)&part[row * 4];
        float l = pl[0] + pl[1] + pl[2] + pl[3];
        bool qp = read_mask(qpad, b * SEQ + q0 + row, mode);
        f[m][r] = (l > 0.0f && !qp) ? 1.0f / l : 0.0f;
      }
#pragma unroll
    for (int m = 0; m < 2; ++m)
#pragma unroll
      for (int n = 0; n < 8; ++n) {
        int dv = ((n >> 2) * 256) + w * 64 + (n & 3) * 16 + l15;
#pragma unroll
        for (int r = 0; r < 4; ++r) {
          int row = m * 16 + lg * 4 + r;
          out[(size_t)(b * SEQ + q0 + row) * DV + dv] = o[m][n][r] * f[m][r];
        }
      }
  }
}

// ---------------- workspace layout (bytes) ----------------
// Wt (3x bf16 [512][1024]) : 0        .. 3145728
// Qb / Kb / Vb bf16        : 3145728  .. 53477376  (3 x 16777216)
// Vt bf16 [8][512][2048]   : 53477376 .. 70254592
// mask-mode flag (int)     : 70254592 .. 70254596
extern "C" void kernel_launch(void* const* d_in, const int* in_sizes, int n_in,
                              void* d_out, int out_size, void* d_ws, size_t ws_size,
                              hipStream_t stream) {
  const float* sq  = (const float*)d_in[0];
  const float* skv = (const float*)d_in[1];
  const void* qp   = d_in[2];
  const void* kvp  = d_in[3];
  const float* Wq  = (const float*)d_in[4];
  const float* Wk  = (const float*)d_in[5];
  const float* Wv  = (const float*)d_in[6];
  char* ws = (char*)d_ws;

  u16* Wts  = (u16*)ws;
  u16* outs = (u16*)(ws + 3145728);
  u16* Qb = outs;
  u16* Kb = outs + 8388608;
  u16* Vb = outs + 16777216;
  u16* Vt = (u16*)(ws + 53477376);
  int* flag = (int*)(ws + 70254592);

  wt_transpose<<<dim3(32, 16, 3), dim3(32, 8, 1), 0, stream>>>(Wq, Wk, Wv, Wts);
  detect_mode<<<1, 256, 0, stream>>>((const int*)qp, flag);
  proj_gemm<<<dim3(4, 128, 3), dim3(256), 0, stream>>>(sq, skv, Wts, outs);
  v_transpose<<<dim3(8, 256), dim3(256), 0, stream>>>(Vb, Vt);
  attn_kernel<<<dim3(512), dim3(256), 0, stream>>>(Qb, Kb, Vt, qp, kvp, flag,
                                                   (float*)d_out);
}

// Round 3
// 471.944 us; speedup vs baseline: 1.1991x; 1.1991x over previous
//
#include <hip/hip_runtime.h>

typedef unsigned short u16;
typedef unsigned int   u32;
typedef __attribute__((ext_vector_type(4))) float  f32x4;
typedef __attribute__((ext_vector_type(8))) __bf16 bf16x8;

// ---------------- constants ----------------
#define BATCH 8
#define SEQ   2048
#define DMODEL 1024
#define DK    512
#define DV    512
#define SCALE 0.044194173824159216f

__device__ __forceinline__ u16 f2bf(float f) {
  u32 u = __float_as_uint(f);
  return (u16)((u + 0x7fffu + ((u >> 16) & 1u)) >> 16);
}

// mask dtype mode: 0 = int32, 1 = uint8, 2 = float32
__device__ __forceinline__ bool read_mask(const void* p, int idx, int mode) {
  if (mode == 1) return ((const unsigned char*)p)[idx] != 0;
  if (mode == 2) return ((const float*)p)[idx] != 0.0f;
  return ((const int*)p)[idx] != 0;
}

// async global->LDS, 16B per lane, dest = lds + lane*16 (wave-uniform base)
__device__ __forceinline__ void gl_lds16(const u16* g, u16* l) {
  __builtin_amdgcn_global_load_lds(
      (const __attribute__((address_space(1))) u32*)g,
      (__attribute__((address_space(3))) u32*)l, 16, 0, 0);
}

// ---------------- kernel 0: detect mask dtype ----------------
__global__ void detect_mode(const int* __restrict__ qp, int* __restrict__ flag) {
  __shared__ int f;
  if (threadIdx.x == 0) f = 0;
  __syncthreads();
  int local = 0;
  for (int i = threadIdx.x; i < 4096; i += 256) {
    int v = qp[i];
    if (v == 0x3F800000) local |= 2;
    else if (v != 0 && v != 1 && v != -1) local |= 1;
  }
  if (local) atomicOr(&f, local);
  __syncthreads();
  if (threadIdx.x == 0) {
    int m = 0;
    if (f & 2) m = 2; else if (f & 1) m = 1;
    *flag = m;
  }
}

// ---------------- kernel 1: W [1024][512] f32 -> Wt [512][1024] bf16 ----------------
__global__ __launch_bounds__(256) void wt_transpose(const float* __restrict__ W0,
                                                    const float* __restrict__ W1,
                                                    const float* __restrict__ W2,
                                                    u16* __restrict__ dst) {
  const float* W = (blockIdx.z == 0) ? W0 : (blockIdx.z == 1) ? W1 : W2;
  u16* out = dst + (size_t)blockIdx.z * (DK * DMODEL);
  __shared__ float T[32][33];
  int k0 = blockIdx.x * 32, n0 = blockIdx.y * 32;
  int tx = threadIdx.x, ty = threadIdx.y;
#pragma unroll
  for (int i = 0; i < 4; ++i) {
    int r = ty + i * 8;
    T[r][tx] = W[(size_t)(k0 + r) * DK + n0 + tx];
  }
  __syncthreads();
#pragma unroll
  for (int i = 0; i < 4; ++i) {
    int r = ty + i * 8;
    out[(size_t)(n0 + r) * DMODEL + k0 + tx] = f2bf(T[tx][r]);
  }
}

// ---------------- kernel 2: f32 -> bf16 elementwise (A pre-convert) ----------------
__global__ __launch_bounds__(256) void convert_bf16(const float* __restrict__ src,
                                                    u16* __restrict__ dst) {
  int i = (blockIdx.x * 256 + threadIdx.x) * 8;
  f32x4 a = *(const f32x4*)(src + i);
  f32x4 b = *(const f32x4*)(src + i + 4);
  uint4 o;
  o.x = (u32)f2bf(a[0]) | ((u32)f2bf(a[1]) << 16);
  o.y = (u32)f2bf(a[2]) | ((u32)f2bf(a[3]) << 16);
  o.z = (u32)f2bf(b[0]) | ((u32)f2bf(b[1]) << 16);
  o.w = (u32)f2bf(b[2]) | ((u32)f2bf(b[3]) << 16);
  *(uint4*)(dst + i) = o;
}

// ---------------- kernel 3: projection GEMM (m97 structure) ----------------
// C[16384][512] = A(bf16)[16384][1024] * Wt(bf16)[512][1024]^T
// 128x128 tile, BK=64, global_load_lds w=16, XOR-8 LDS swizzle.
// Epilogue writes MFMA-fragment layouts:
//   Qf/Kf (is_v=0): off(row,d) = (row>>4)*8192 + (d>>5)*512 + (row&15)*32 + (d&31)
//   Vf    (is_v=1): off(dv,s)  = b*S*DV + (dv>>4)*32768 + (s>>5)*512 + (dv&15)*32 + (s&31)
__global__ __launch_bounds__(256, 3) void proj_gemm(const u16* __restrict__ A,
                                                    const u16* __restrict__ Wt_base,
                                                    int z0, u16* __restrict__ dst0,
                                                    u16* __restrict__ dst1) {
  int z = z0 + blockIdx.z;
  const u16* Wt = Wt_base + (size_t)z * (DK * DMODEL);
  u16* dst = (z == 2) ? dst1 : dst0;
  int n0 = blockIdx.x * 128, m0 = blockIdx.y * 128;

  __shared__ __align__(16) u16 As[128 * 64];
  __shared__ __align__(16) u16 Bs[128 * 64];

  int tid = threadIdx.x, lane = tid & 63, w = tid >> 6;
  int wm = w & 1, wn = w >> 1;
  int l15 = lane & 15, lg = lane >> 4;
  int r3 = lane >> 3, c7 = lane & 7;
  int csw = c7 ^ r3;               // swizzled global chunk for this lane

  f32x4 acc[4][4];
#pragma unroll
  for (int m = 0; m < 4; ++m)
#pragma unroll
    for (int n = 0; n < 4; ++n) acc[m][n] = (f32x4)0.0f;

  for (int k0 = 0; k0 < DMODEL; k0 += 64) {
    __syncthreads(); // prior frag reads done
#pragma unroll
    for (int u = 0; u < 4; ++u) {
      int t = w * 4 + u; // instr covers rows t*8 .. t*8+7
      gl_lds16(A  + (size_t)(m0 + t * 8 + r3) * DMODEL + k0 + csw * 8, &As[t * 512]);
      gl_lds16(Wt + (size_t)(n0 + t * 8 + r3) * DMODEL + k0 + csw * 8, &Bs[t * 512]);
    }
    __syncthreads(); // drain
#pragma unroll
    for (int ks = 0; ks < 2; ++ks) {
      bf16x8 af[4], bfv[4];
#pragma unroll
      for (int m = 0; m < 4; ++m) {
        int row = wm * 64 + m * 16 + l15;
        af[m] = *(const bf16x8*)&As[row * 64 + (((ks * 4 + lg) ^ (l15 & 7)) * 8)];
      }
#pragma unroll
      for (int n = 0; n < 4; ++n) {
        int row = wn * 64 + n * 16 + l15;
        bfv[n] = *(const bf16x8*)&Bs[row * 64 + (((ks * 4 + lg) ^ (l15 & 7)) * 8)];
      }
#pragma unroll
      for (int m = 0; m < 4; ++m)
#pragma unroll
        for (int n = 0; n < 4; ++n)
          acc[m][n] = __builtin_amdgcn_mfma_f32_16x16x32_bf16(af[m], bfv[n], acc[m][n], 0, 0, 0);
    }
  }

  if (z != 2) {
    // Qf/Kf fragment layout (global row carries batch: b*S*DK == (row>>4)*8192 base)
#pragma unroll
    for (int m = 0; m < 4; ++m) {
      int rowb = m0 + wm * 64 + m * 16;
#pragma unroll
      for (int n = 0; n < 4; ++n) {
        int col = n0 + wn * 64 + n * 16 + l15;
        size_t base = (size_t)(rowb >> 4) * 8192 + (size_t)(col >> 5) * 512 + (col & 31);
#pragma unroll
        for (int r = 0; r < 4; ++r)
          dst[base + (lg * 4 + r) * 32] = f2bf(acc[m][n][r]);
      }
    }
  } else {
    // Vf fragment layout (transposed): pack 4 consecutive s into one 8B store
#pragma unroll
    for (int m = 0; m < 4; ++m) {
      int row0 = m0 + wm * 64 + m * 16 + lg * 4;
      int b = row0 >> 11, s0 = row0 & 2047;
#pragma unroll
      for (int n = 0; n < 4; ++n) {
        int dv = n0 + wn * 64 + n * 16 + l15;
        size_t off = (size_t)b * (SEQ * DV) + (size_t)(dv >> 4) * 32768 +
                     (size_t)(s0 >> 5) * 512 + (dv & 15) * 32 + (s0 & 31);
        u16 tmp[4] __attribute__((aligned(8)));
#pragma unroll
        for (int r = 0; r < 4; ++r) tmp[r] = f2bf(acc[m][n][r]);
        *(uint2*)&dst[off] = *(const uint2*)tmp;
      }
    }
  }
}

// ---------------- kernel 4: flash attention, fragment-direct loads ----------------
// 32 q-rows/block, Tk=64. Wave w: m-frag (w>>1), key half (w&1) in S phase;
// dv slice w*128..+127 in PV phase. All Q/K/V loads are 1KB-coalesced frag loads.
__global__ __launch_bounds__(256, 2) void attn_kernel(
    const u16* __restrict__ Qf, const u16* __restrict__ Kf,
    const u16* __restrict__ Vf, const void* __restrict__ qpad,
    const void* __restrict__ kvpad, const int* __restrict__ flag,
    float* __restrict__ out) {
  __shared__ __align__(16) u16 Pbuf[32 * 72];
  __shared__ float partm[32 * 2];
  __shared__ float ald[32];
  __shared__ float partl[32 * 2];

  int tid = threadIdx.x;
  int lane = tid & 63, w = tid >> 6;
  int l15 = lane & 15, lg = lane >> 4;
  int wk = w & 1;       // key half in S phase
  int m  = w >> 1;      // m-frag in S phase
  int bi = blockIdx.x;
  int j = bi & 63, b = bi >> 6;
  int qt = (j & 1) ? (63 - (j >> 1)) : (j >> 1); // adjacent blocks: cheap+expensive
  int q0 = qt * 32;
  int mode = *flag;
  int lanoff = l15 * 32 + lg * 8;

  const u16* Qb = Qf + (size_t)b * (SEQ * DK);
  const u16* Kb = Kf + (size_t)b * (SEQ * DK);
  const u16* Vb = Vf + (size_t)b * (SEQ * DV);

  // resident Q fragment: 16 rows (q0 + m*16 ..), 512 d -> 64 VGPRs
  bf16x8 qf[16];
  {
    const u16* qp = Qb + (size_t)(qt * 2 + m) * 8192 + lanoff;
#pragma unroll
    for (int ks = 0; ks < 16; ++ks) qf[ks] = *(const bf16x8*)(qp + ks * 512);
  }

  f32x4 o[2][8];
#pragma unroll
  for (int m2 = 0; m2 < 2; ++m2)
#pragma unroll
    for (int n = 0; n < 8; ++n) o[m2][n] = (f32x4)0.0f;

  float mo[4], lsum[4];
#pragma unroll
  for (int r = 0; r < 4; ++r) { mo[r] = -1e38f; lsum[r] = 0.0f; }

  int nkt = (q0 + 95) >> 6;

  for (int kt = 0; kt < nkt; ++kt) {
    int k0 = kt * 64;

    // ---- S = Q K^T : 2 key groups x 16 k-slices, coalesced frag loads ----
    f32x4 s0 = (f32x4)0.0f, s1 = (f32x4)0.0f;
    {
      const u16* kp0 = Kb + (size_t)((k0 >> 4) + wk * 2) * 8192 + lanoff;
      const u16* kp1 = kp0 + 8192;
#pragma unroll
      for (int ks = 0; ks < 16; ++ks) {
        bf16x8 b0 = *(const bf16x8*)(kp0 + ks * 512);
        bf16x8 b1 = *(const bf16x8*)(kp1 + ks * 512);
        s0 = __builtin_amdgcn_mfma_f32_16x16x32_bf16(qf[ks], b0, s0, 0, 0, 0);
        s1 = __builtin_amdgcn_mfma_f32_16x16x32_bf16(qf[ks], b1, s1, 0, 0, 0);
      }
    }

    // ---- scale + mask ----
    float sv[2][4];
#pragma unroll
    for (int kg = 0; kg < 2; ++kg) {
      int key = k0 + wk * 32 + kg * 16 + l15;
      bool kvm = read_mask(kvpad, b * SEQ + key, mode);
#pragma unroll
      for (int r = 0; r < 4; ++r) {
        int qrow = q0 + m * 16 + lg * 4 + r;
        float x = (kg == 0 ? s0[r] : s1[r]) * SCALE;
        sv[kg][r] = (kvm || key > qrow) ? -__builtin_inff() : x;
      }
    }

    // ---- wave-local row max over this wave's 32 keys ----
    float wmax[4];
#pragma unroll
    for (int r = 0; r < 4; ++r) wmax[r] = fmaxf(sv[0][r], sv[1][r]);
#pragma unroll
    for (int d = 1; d < 16; d <<= 1)
#pragma unroll
      for (int r = 0; r < 4; ++r) wmax[r] = fmaxf(wmax[r], __shfl_xor(wmax[r], d));
    if (l15 == 0) {
#pragma unroll
      for (int r = 0; r < 4; ++r) partm[(m * 16 + lg * 4 + r) * 2 + wk] = wmax[r];
    }
    __syncthreads(); // B1

    // ---- online softmax update ----
    float al[4], ws[4];
#pragma unroll
    for (int r = 0; r < 4; ++r) {
      int row = m * 16 + lg * 4 + r;
      float tm = fmaxf(partm[row * 2], partm[row * 2 + 1]);
      float mn = fmaxf(mo[r], fmaxf(tm, -1e38f));
      al[r] = __expf(mo[r] - mn);
      mo[r] = mn;
      float p0 = __expf(sv[0][r] - mn);
      float p1 = __expf(sv[1][r] - mn);
      Pbuf[row * 72 + wk * 32 + l15] = f2bf(p0);
      Pbuf[row * 72 + wk * 32 + 16 + l15] = f2bf(p1);
      ws[r] = p0 + p1;
    }
#pragma unroll
    for (int d = 1; d < 16; d <<= 1)
#pragma unroll
      for (int r = 0; r < 4; ++r) ws[r] += __shfl_xor(ws[r], d);
#pragma unroll
    for (int r = 0; r < 4; ++r) lsum[r] = lsum[r] * al[r] + ws[r];
    if (wk == 0 && l15 == 0) {
#pragma unroll
      for (int r = 0; r < 4; ++r) ald[m * 16 + lg * 4 + r] = al[r];
    }
    __syncthreads(); // B2: Pbuf + ald visible

    // ---- rescale O ----
    float ar[2][4];
#pragma unroll
    for (int m2 = 0; m2 < 2; ++m2)
#pragma unroll
      for (int r = 0; r < 4; ++r) ar[m2][r] = ald[m2 * 16 + lg * 4 + r];
#pragma unroll
    for (int m2 = 0; m2 < 2; ++m2)
#pragma unroll
      for (int n = 0; n < 8; ++n)
#pragma unroll
        for (int r = 0; r < 4; ++r) o[m2][n][r] *= ar[m2][r];

    // ---- O += P V : coalesced V^T fragment loads ----
    {
      const u16* vpb = Vb + (size_t)(w * 8) * 32768 + (size_t)(k0 >> 5) * 512 + lanoff;
#pragma unroll
      for (int ks = 0; ks < 2; ++ks) {
        bf16x8 pa0 = *(const bf16x8*)&Pbuf[(l15) * 72 + ks * 32 + lg * 8];
        bf16x8 pa1 = *(const bf16x8*)&Pbuf[(16 + l15) * 72 + ks * 32 + lg * 8];
#pragma unroll
        for (int n = 0; n < 4; ++n) {
          bf16x8 bv0 = *(const bf16x8*)(vpb + (size_t)(n * 2) * 32768 + ks * 512);
          bf16x8 bv1 = *(const bf16x8*)(vpb + (size_t)(n * 2 + 1) * 32768 + ks * 512);
          o[0][n * 2]     = __builtin_amdgcn_mfma_f32_16x16x32_bf16(pa0, bv0, o[0][n * 2], 0, 0, 0);
          o[1][n * 2]     = __builtin_amdgcn_mfma_f32_16x16x32_bf16(pa1, bv0, o[1][n * 2], 0, 0, 0);
          o[0][n * 2 + 1] = __builtin_amdgcn_mfma_f32_16x16x32_bf16(pa0, bv1, o[0][n * 2 + 1], 0, 0, 0);
          o[1][n * 2 + 1] = __builtin_amdgcn_mfma_f32_16x16x32_bf16(pa1, bv1, o[1][n * 2 + 1], 0, 0, 0);
        }
      }
    }
  }

  // ---- epilogue ----
  if (l15 == 0) {
#pragma unroll
    for (int r = 0; r < 4; ++r) partl[(m * 16 + lg * 4 + r) * 2 + wk] = lsum[r];
  }
  __syncthreads();
  {
    float f[2][4];
#pragma unroll
    for (int m2 = 0; m2 < 2; ++m2)
#pragma unroll
      for (int r = 0; r < 4; ++r) {
        int row = m2 * 16 + lg * 4 + r;
        float l = partl[row * 2] + partl[row * 2 + 1];
        bool qp = read_mask(qpad, b * SEQ + q0 + row, mode);
        f[m2][r] = (l > 0.0f && !qp) ? 1.0f / l : 0.0f;
      }
#pragma unroll
    for (int m2 = 0; m2 < 2; ++m2)
#pragma unroll
      for (int n = 0; n < 8; ++n) {
        int dv = w * 128 + n * 16 + l15;
#pragma unroll
        for (int r = 0; r < 4; ++r) {
          int row = m2 * 16 + lg * 4 + r;
          out[(size_t)(b * SEQ + q0 + row) * DV + dv] = o[m2][n][r] * f[m2][r];
        }
      }
  }
}

// ---------------- workspace layout (bytes), overlay to stay <= ~87 MB ----------------
// Abf  [16384][1024] bf16 : 0         .. 33554432   (sq first, then skv - reused)
// Qf                      : 33554432  .. 50331648
// Kf                      : 50331648  .. 67108864
// Vf                      : 67108864  .. 83886080
// Wt (3x [512][1024] bf16): 83886080  .. 87031808
// flag (int)              : 87031808  .. 87031812
extern "C" void kernel_launch(void* const* d_in, const int* in_sizes, int n_in,
                              void* d_out, int out_size, void* d_ws, size_t ws_size,
                              hipStream_t stream) {
  const float* sq  = (const float*)d_in[0];
  const float* skv = (const float*)d_in[1];
  const void* qp   = d_in[2];
  const void* kvp  = d_in[3];
  const float* Wq  = (const float*)d_in[4];
  const float* Wk  = (const float*)d_in[5];
  const float* Wv  = (const float*)d_in[6];
  char* ws = (char*)d_ws;

  u16* Abf = (u16*)ws;
  u16* Qf  = (u16*)(ws + 33554432);
  u16* Kf  = (u16*)(ws + 50331648);
  u16* Vf  = (u16*)(ws + 67108864);
  u16* Wt  = (u16*)(ws + 83886080);
  int* flag = (int*)(ws + 87031808);

  wt_transpose<<<dim3(32, 16, 3), dim3(32, 8, 1), 0, stream>>>(Wq, Wk, Wv, Wt);
  detect_mode<<<1, 256, 0, stream>>>((const int*)qp, flag);

  // sq -> Abf, project Q
  convert_bf16<<<8192, 256, 0, stream>>>(sq, Abf);
  proj_gemm<<<dim3(4, 128, 1), dim3(256), 0, stream>>>(Abf, Wt, 0, Qf, Qf);

  // skv -> Abf (reuse), project K and V in one launch (z = 1, 2)
  convert_bf16<<<8192, 256, 0, stream>>>(skv, Abf);
  proj_gemm<<<dim3(4, 128, 2), dim3(256), 0, stream>>>(Abf, Wt, 1, Kf, Vf);

  attn_kernel<<<dim3(512), dim3(256), 0, stream>>>(Qf, Kf, Vf, qp, kvp, flag,
                                                   (float*)d_out);
}